// Round 3
// baseline (35.523 us; speedup 1.0000x reference)
//
#include <hip/hip_runtime.h>

#define FK_NQ 7
#define FK_BLOCK 256
#define REC 32   // floats per joint record in d_ws

// Record layout (floats), per joint j at cst + j*REC:
//  [0..8]   D  = R_joint - C
//  [9..17]  B1 = R_joint @ cross(w) / |w|
//  [18..26] C  = (R_joint @ w) w^T / |w|^2
//  [27..29] t  = joint_xyz
//  [30]     n  = |w|
// After 7 records: cst[7*REC + 0..2] = link_xyz[idx]
// Then per thread:  A_j = cv*D + sv*B1 + C  ==  R_joint @ Rodrigues(w, q)

__global__ void fk_setup(const float* __restrict__ joint_xyz,
                         const float* __restrict__ joint_rpy,
                         const float* __restrict__ joint_axis,
                         const float* __restrict__ link_xyz,
                         const int*   __restrict__ idxp,
                         float* __restrict__ cst)
{
    const int j = threadIdx.x;
    if (j < FK_NQ) {
        float rr = joint_rpy[j*3+0], pp = joint_rpy[j*3+1], yy = joint_rpy[j*3+2];
        float sr, cr, sp2, cp2, sy, cy;
        __sincosf(rr, &sr, &cr);
        __sincosf(pp, &sp2, &cp2);
        __sincosf(yy, &sy, &cy);
        float R[9];
        R[0] = cy*cp2;  R[1] = cy*sp2*sr - sy*cr;  R[2] = cy*sp2*cr + sy*sr;
        R[3] = sy*cp2;  R[4] = sy*sp2*sr + cy*cr;  R[5] = sy*sp2*cr - cy*sr;
        R[6] = -sp2;    R[7] = cp2*sr;             R[8] = cp2*cr;

        float w0 = joint_axis[j*3+0], w1 = joint_axis[j*3+1], w2 = joint_axis[j*3+2];
        float w[3] = {w0, w1, w2};
        float n2 = w0*w0 + w1*w1 + w2*w2;
        float n  = sqrtf(n2);
        float ninv = 1.0f/n, n2inv = 1.0f/n2;

        float* c = cst + j*REC;
        #pragma unroll
        for (int r = 0; r < 3; ++r) {
            // B1 row r = cross(R_row, w) / n
            c[9+r*3+0] = (R[r*3+1]*w2 - R[r*3+2]*w1) * ninv;
            c[9+r*3+1] = (R[r*3+2]*w0 - R[r*3+0]*w2) * ninv;
            c[9+r*3+2] = (R[r*3+0]*w1 - R[r*3+1]*w0) * ninv;
            float u = (R[r*3+0]*w0 + R[r*3+1]*w1 + R[r*3+2]*w2) * n2inv;
            #pragma unroll
            for (int cc = 0; cc < 3; ++cc) {
                float C = u * w[cc];
                c[18+r*3+cc] = C;
                c[r*3+cc]    = R[r*3+cc] - C;
            }
        }
        c[27] = joint_xyz[j*3+0];
        c[28] = joint_xyz[j*3+1];
        c[29] = joint_xyz[j*3+2];
        c[30] = n;
        c[31] = 0.0f;
    } else if (j == FK_NQ) {
        const int ix = idxp[0];
        cst[FK_NQ*REC+0] = link_xyz[ix*3+0];
        cst[FK_NQ*REC+1] = link_xyz[ix*3+1];
        cst[FK_NQ*REC+2] = link_xyz[ix*3+2];
    }
}

__device__ __forceinline__ void form_A(const float* __restrict__ cst, int j,
                                       float sv, float cv, float* A)
{
    const float* c = cst + j*REC;
    #pragma unroll
    for (int k = 0; k < 9; ++k)
        A[k] = fmaf(cv, c[k], fmaf(sv, c[9+k], c[18+k]));
}

__device__ __forceinline__ void mul33(const float* X, const float* Y, float* Z)
{
    #pragma unroll
    for (int r = 0; r < 3; ++r) {
        float x0 = X[r*3+0], x1 = X[r*3+1], x2 = X[r*3+2];
        #pragma unroll
        for (int c = 0; c < 3; ++c)
            Z[r*3+c] = x0*Y[c] + x1*Y[3+c] + x2*Y[6+c];
    }
}

__global__ __launch_bounds__(FK_BLOCK) void fk_main(
    const float* __restrict__ q,
    const float* __restrict__ cst,
    float* __restrict__ out,
    int nb)
{
    __shared__ float sq[FK_BLOCK * FK_NQ];
    const int tid = threadIdx.x;
    const long bbase = (long)blockIdx.x * FK_BLOCK;
    const long qbase = bbase * FK_NQ;
    const long qtot  = (long)nb * FK_NQ;
    #pragma unroll
    for (int i = tid; i < FK_BLOCK * FK_NQ; i += FK_BLOCK) {
        long g = qbase + i;
        sq[i] = (g < qtot) ? q[g] : 0.0f;
    }
    __syncthreads();

    const long b = bbase + tid;
    if (b >= nb) return;

    // 7 independent sincos up front (ILP)
    float sv[FK_NQ], cv[FK_NQ];
    #pragma unroll
    for (int j = 0; j < FK_NQ; ++j) {
        float x = cst[j*REC+30] * sq[tid*FK_NQ + j];
        __sincosf(x, &sv[j], &cv[j]);
    }

    // ---- level 1: three independent pair-composes + A6 (with link fold) ----
    float A0[9], A1[9], P01[9], t01[3];
    form_A(cst, 0, sv[0], cv[0], A0);
    form_A(cst, 1, sv[1], cv[1], A1);
    mul33(A0, A1, P01);
    #pragma unroll
    for (int r = 0; r < 3; ++r)
        t01[r] = A0[r*3+0]*cst[1*REC+27] + A0[r*3+1]*cst[1*REC+28]
               + A0[r*3+2]*cst[1*REC+29] + cst[0*REC+27+r];

    float A2[9], A3[9], P23[9], t23[3];
    form_A(cst, 2, sv[2], cv[2], A2);
    form_A(cst, 3, sv[3], cv[3], A3);
    mul33(A2, A3, P23);
    #pragma unroll
    for (int r = 0; r < 3; ++r)
        t23[r] = A2[r*3+0]*cst[3*REC+27] + A2[r*3+1]*cst[3*REC+28]
               + A2[r*3+2]*cst[3*REC+29] + cst[2*REC+27+r];

    float A4[9], A5[9], P45[9], t45[3];
    form_A(cst, 4, sv[4], cv[4], A4);
    form_A(cst, 5, sv[5], cv[5], A5);
    mul33(A4, A5, P45);
    #pragma unroll
    for (int r = 0; r < 3; ++r)
        t45[r] = A4[r*3+0]*cst[5*REC+27] + A4[r*3+1]*cst[5*REC+28]
               + A4[r*3+2]*cst[5*REC+29] + cst[4*REC+27+r];

    float A6[9], t6f[3];
    form_A(cst, 6, sv[6], cv[6], A6);
    // fold link offset p into joint 6: t6f = A6*p + t6
    #pragma unroll
    for (int r = 0; r < 3; ++r)
        t6f[r] = A6[r*3+0]*cst[FK_NQ*REC+0] + A6[r*3+1]*cst[FK_NQ*REC+1]
               + A6[r*3+2]*cst[FK_NQ*REC+2] + cst[6*REC+27+r];

    // ---- level 2 ----
    float P03[9], t03[3];
    mul33(P01, P23, P03);
    #pragma unroll
    for (int r = 0; r < 3; ++r)
        t03[r] = P01[r*3+0]*t23[0] + P01[r*3+1]*t23[1] + P01[r*3+2]*t23[2] + t01[r];

    float P46[9], t46[3];
    mul33(P45, A6, P46);
    #pragma unroll
    for (int r = 0; r < 3; ++r)
        t46[r] = P45[r*3+0]*t6f[0] + P45[r*3+1]*t6f[1] + P45[r*3+2]*t6f[2] + t45[r];

    // ---- level 3 ----
    float M[9], tM[3];
    mul33(P03, P46, M);
    #pragma unroll
    for (int r = 0; r < 3; ++r)
        tM[r] = P03[r*3+0]*t46[0] + P03[r*3+1]*t46[1] + P03[r*3+2]*t46[2] + t03[r];

    float4* o = (float4*)(out + b*16);
    float4 row;
    row.x = M[0]; row.y = M[1]; row.z = M[2]; row.w = tM[0];
    o[0] = row;
    row.x = M[3]; row.y = M[4]; row.z = M[5]; row.w = tM[1];
    o[1] = row;
    row.x = M[6]; row.y = M[7]; row.z = M[8]; row.w = tM[2];
    o[2] = row;
    row.x = 0.0f; row.y = 0.0f; row.z = 0.0f; row.w = 1.0f;
    o[3] = row;
}

extern "C" void kernel_launch(void* const* d_in, const int* in_sizes, int n_in,
                              void* d_out, int out_size, void* d_ws, size_t ws_size,
                              hipStream_t stream) {
    const float* q          = (const float*)d_in[0];
    const float* joint_xyz  = (const float*)d_in[1];
    const float* joint_rpy  = (const float*)d_in[2];
    const float* joint_axis = (const float*)d_in[3];
    const float* link_xyz   = (const float*)d_in[4];
    const int*   idxp       = (const int*)d_in[5];
    float* out = (float*)d_out;
    float* cst = (float*)d_ws;

    const int nb = in_sizes[0] / FK_NQ;
    const int grid = (nb + FK_BLOCK - 1) / FK_BLOCK;

    fk_setup<<<1, 64, 0, stream>>>(joint_xyz, joint_rpy, joint_axis,
                                   link_xyz, idxp, cst);
    fk_main<<<grid, FK_BLOCK, 0, stream>>>(q, cst, out, nb);
}

// Round 4
// 29.979 us; speedup vs baseline: 1.1849x; 1.1849x over previous
//
#include <hip/hip_runtime.h>

#define FK_NQ 7
#define FK_BLOCK 256
#define FK_IT 2          // batch items per thread
#define REC 32           // floats per joint record in d_ws

// Record layout (floats), per joint j at cst + j*REC:
//  [0..8]   D  = R_joint - C
//  [9..17]  B1 = R_joint @ cross(w) / |w|
//  [18..26] C  = (R_joint @ w) w^T / |w|^2
//  [27..29] t  = joint_xyz
//  [30]     n  = |w|
// After 7 records: cst[7*REC + 0..2] = link_xyz[idx]
// Per thread:  A_j = cv*D + sv*B1 + C  ==  R_joint @ Rodrigues(w, q)

__global__ void fk_setup(const float* __restrict__ joint_xyz,
                         const float* __restrict__ joint_rpy,
                         const float* __restrict__ joint_axis,
                         const float* __restrict__ link_xyz,
                         const int*   __restrict__ idxp,
                         float* __restrict__ cst)
{
    const int j = threadIdx.x;
    if (j < FK_NQ) {
        float rr = joint_rpy[j*3+0], pp = joint_rpy[j*3+1], yy = joint_rpy[j*3+2];
        float sr, cr, sp2, cp2, sy, cy;
        __sincosf(rr, &sr, &cr);
        __sincosf(pp, &sp2, &cp2);
        __sincosf(yy, &sy, &cy);
        float R[9];
        R[0] = cy*cp2;  R[1] = cy*sp2*sr - sy*cr;  R[2] = cy*sp2*cr + sy*sr;
        R[3] = sy*cp2;  R[4] = sy*sp2*sr + cy*cr;  R[5] = sy*sp2*cr - cy*sr;
        R[6] = -sp2;    R[7] = cp2*sr;             R[8] = cp2*cr;

        float w0 = joint_axis[j*3+0], w1 = joint_axis[j*3+1], w2 = joint_axis[j*3+2];
        float w[3] = {w0, w1, w2};
        float n2 = w0*w0 + w1*w1 + w2*w2;
        float n  = sqrtf(n2);
        float ninv = 1.0f/n, n2inv = 1.0f/n2;

        float* c = cst + j*REC;
        #pragma unroll
        for (int r = 0; r < 3; ++r) {
            c[9+r*3+0] = (R[r*3+1]*w2 - R[r*3+2]*w1) * ninv;
            c[9+r*3+1] = (R[r*3+2]*w0 - R[r*3+0]*w2) * ninv;
            c[9+r*3+2] = (R[r*3+0]*w1 - R[r*3+1]*w0) * ninv;
            float u = (R[r*3+0]*w0 + R[r*3+1]*w1 + R[r*3+2]*w2) * n2inv;
            #pragma unroll
            for (int cc = 0; cc < 3; ++cc) {
                float C = u * w[cc];
                c[18+r*3+cc] = C;
                c[r*3+cc]    = R[r*3+cc] - C;
            }
        }
        c[27] = joint_xyz[j*3+0];
        c[28] = joint_xyz[j*3+1];
        c[29] = joint_xyz[j*3+2];
        c[30] = n;
        c[31] = 0.0f;
    } else if (j == FK_NQ) {
        const int ix = idxp[0];
        cst[FK_NQ*REC+0] = link_xyz[ix*3+0];
        cst[FK_NQ*REC+1] = link_xyz[ix*3+1];
        cst[FK_NQ*REC+2] = link_xyz[ix*3+2];
    }
}

__global__ __launch_bounds__(FK_BLOCK) void fk_main(
    const float* __restrict__ q,
    const float* __restrict__ cst,
    float* __restrict__ out,
    int nb)
{
    const long b0 = ((long)blockIdx.x * FK_BLOCK + threadIdx.x) * FK_IT;
    if (b0 >= nb) return;
    const int nit = (b0 + FK_IT <= nb) ? FK_IT : (int)(nb - b0);

    // Per-thread q: FK_IT*7 contiguous floats (wave reads one contiguous span)
    float qq[FK_IT * FK_NQ];
    {
        const float* qp = q + b0 * FK_NQ;
        if (nit == FK_IT) {
            #pragma unroll
            for (int i = 0; i < FK_IT * FK_NQ; ++i) qq[i] = qp[i];
        } else {
            #pragma unroll
            for (int i = 0; i < FK_IT * FK_NQ; ++i)
                qq[i] = (i < nit * FK_NQ) ? qp[i] : 0.0f;
        }
    }

    // FK_IT independent chains, fully unrolled and interleaved (ILP)
    float M[FK_IT][9], t[FK_IT][3];

    #pragma unroll
    for (int j = 0; j < FK_NQ; ++j) {
        #pragma unroll
        for (int k = 0; k < FK_IT; ++k) {
            float sv, cv;
            __sincosf(cst[j*REC+30] * qq[k*FK_NQ + j], &sv, &cv);
            float A[9];
            #pragma unroll
            for (int e = 0; e < 9; ++e)
                A[e] = fmaf(cv, cst[j*REC+e], fmaf(sv, cst[j*REC+9+e], cst[j*REC+18+e]));
            if (j == 0) {
                #pragma unroll
                for (int e = 0; e < 9; ++e) M[k][e] = A[e];
                t[k][0] = cst[27]; t[k][1] = cst[28]; t[k][2] = cst[29];
            } else {
                const float t0 = cst[j*REC+27], t1 = cst[j*REC+28], t2 = cst[j*REC+29];
                #pragma unroll
                for (int r = 0; r < 3; ++r)
                    t[k][r] += M[k][r*3+0]*t0 + M[k][r*3+1]*t1 + M[k][r*3+2]*t2;
                #pragma unroll
                for (int r = 0; r < 3; ++r) {
                    float m0 = M[k][r*3+0], m1 = M[k][r*3+1], m2 = M[k][r*3+2];
                    #pragma unroll
                    for (int c = 0; c < 3; ++c)
                        M[k][r*3+c] = m0*A[c] + m1*A[3+c] + m2*A[6+c];
                }
            }
        }
    }

    const float p0 = cst[FK_NQ*REC+0], p1 = cst[FK_NQ*REC+1], p2 = cst[FK_NQ*REC+2];
    float4* o = (float4*)(out + b0 * 16);
    #pragma unroll
    for (int k = 0; k < FK_IT; ++k) {
        if (k < nit) {
            float4 row;
            #pragma unroll
            for (int r = 0; r < 3; ++r) {
                row.x = M[k][r*3+0]; row.y = M[k][r*3+1]; row.z = M[k][r*3+2];
                row.w = M[k][r*3+0]*p0 + M[k][r*3+1]*p1 + M[k][r*3+2]*p2 + t[k][r];
                o[k*4 + r] = row;
            }
            row.x = 0.0f; row.y = 0.0f; row.z = 0.0f; row.w = 1.0f;
            o[k*4 + 3] = row;
        }
    }
}

extern "C" void kernel_launch(void* const* d_in, const int* in_sizes, int n_in,
                              void* d_out, int out_size, void* d_ws, size_t ws_size,
                              hipStream_t stream) {
    const float* q          = (const float*)d_in[0];
    const float* joint_xyz  = (const float*)d_in[1];
    const float* joint_rpy  = (const float*)d_in[2];
    const float* joint_axis = (const float*)d_in[3];
    const float* link_xyz   = (const float*)d_in[4];
    const int*   idxp       = (const int*)d_in[5];
    float* out = (float*)d_out;
    float* cst = (float*)d_ws;

    const int nb = in_sizes[0] / FK_NQ;
    const int items_per_block = FK_BLOCK * FK_IT;
    const int grid = (nb + items_per_block - 1) / items_per_block;

    fk_setup<<<1, 64, 0, stream>>>(joint_xyz, joint_rpy, joint_axis,
                                   link_xyz, idxp, cst);
    fk_main<<<grid, FK_BLOCK, 0, stream>>>(q, cst, out, nb);
}

// Round 5
// 25.176 us; speedup vs baseline: 1.4110x; 1.1908x over previous
//
#include <hip/hip_runtime.h>

#define FK_NQ 7
#define FK_BLOCK 256
#define JREC 12   // floats per joint record in d_ws

// Record layout (floats), per joint j at cst + j*JREC:
//  [0..3]  qj   : quaternion of R_joint (w,x,y,z), from rpy
//  [4..7]  qjw  : qj (x) (0, w/|w|)   (Hamilton product)
//  [8..10] t_j  : joint_xyz
//  [11]    halfn: 0.5*|w|
// After 7 records: cst[7*JREC + 0..2] = link_xyz[idx]
//
// Joint j total rotation quaternion: cos(halfn*q)*qj + sin(halfn*q)*qjw
// (== quat(R_joint_j) ⊗ quat(Rodrigues(w, q)))

__device__ __forceinline__ void qmul(const float* a, const float* b, float* r)
{
    r[0] = a[0]*b[0] - a[1]*b[1] - a[2]*b[2] - a[3]*b[3];
    r[1] = a[0]*b[1] + a[1]*b[0] + a[2]*b[3] - a[3]*b[2];
    r[2] = a[0]*b[2] - a[1]*b[3] + a[2]*b[0] + a[3]*b[1];
    r[3] = a[0]*b[3] + a[1]*b[2] - a[2]*b[1] + a[3]*b[0];
}

__global__ void fk_setup(const float* __restrict__ joint_xyz,
                         const float* __restrict__ joint_rpy,
                         const float* __restrict__ joint_axis,
                         const float* __restrict__ link_xyz,
                         const int*   __restrict__ idxp,
                         float* __restrict__ cst)
{
    const int j = threadIdx.x;
    if (j < FK_NQ) {
        float rr = joint_rpy[j*3+0], pp = joint_rpy[j*3+1], yy = joint_rpy[j*3+2];
        float sr, cr, sp2, cp2, sy, cy;
        __sincosf(0.5f*rr, &sr, &cr);
        __sincosf(0.5f*pp, &sp2, &cp2);
        __sincosf(0.5f*yy, &sy, &cy);
        // qj = qz ⊗ qy ⊗ qx
        float qx[4] = {cr, sr, 0.f, 0.f};
        float qy[4] = {cp2, 0.f, sp2, 0.f};
        float qz[4] = {cy, 0.f, 0.f, sy};
        float tmp[4], qj[4];
        qmul(qy, qx, tmp);
        qmul(qz, tmp, qj);

        float w0 = joint_axis[j*3+0], w1 = joint_axis[j*3+1], w2 = joint_axis[j*3+2];
        float n  = sqrtf(w0*w0 + w1*w1 + w2*w2);
        float ninv = 1.0f/n;
        float qu[4] = {0.f, w0*ninv, w1*ninv, w2*ninv};
        float qjw[4];
        qmul(qj, qu, qjw);

        float* c = cst + j*JREC;
        c[0] = qj[0];  c[1] = qj[1];  c[2] = qj[2];  c[3] = qj[3];
        c[4] = qjw[0]; c[5] = qjw[1]; c[6] = qjw[2]; c[7] = qjw[3];
        c[8]  = joint_xyz[j*3+0];
        c[9]  = joint_xyz[j*3+1];
        c[10] = joint_xyz[j*3+2];
        c[11] = 0.5f*n;
    } else if (j == FK_NQ) {
        const int ix = idxp[0];
        cst[FK_NQ*JREC+0] = link_xyz[ix*3+0];
        cst[FK_NQ*JREC+1] = link_xyz[ix*3+1];
        cst[FK_NQ*JREC+2] = link_xyz[ix*3+2];
    }
}

__global__ __launch_bounds__(FK_BLOCK, 8) void fk_main(
    const float* __restrict__ q,
    const float* __restrict__ cst,
    float* __restrict__ out,
    int nb)
{
    const int b = blockIdx.x * FK_BLOCK + threadIdx.x;
    if (b >= nb) return;

    const float* qp = q + (long)b * FK_NQ;
    float th[FK_NQ];
    #pragma unroll
    for (int j = 0; j < FK_NQ; ++j) th[j] = qp[j];

    // 7 independent sincos up front (ILP); th regs die here
    float sv[FK_NQ], cv[FK_NQ];
    #pragma unroll
    for (int j = 0; j < FK_NQ; ++j)
        __sincosf(cst[j*JREC+11] * th[j], &sv[j], &cv[j]);

    // j = 0 : Q = qstep0, t = t_0
    float Qw = cv[0]*cst[0] + sv[0]*cst[4];
    float Qx = cv[0]*cst[1] + sv[0]*cst[5];
    float Qy = cv[0]*cst[2] + sv[0]*cst[6];
    float Qz = cv[0]*cst[3] + sv[0]*cst[7];
    float tx = cst[8], ty = cst[9], tz = cst[10];

    #pragma unroll
    for (int j = 1; j < FK_NQ; ++j) {
        const float* c = cst + j*JREC;
        // t += R(Q) * t_j   (quaternion rotate: v + 2(w*(u×v) + u×(u×v)))
        float vx = c[8], vy = c[9], vz = c[10];
        float c1x = Qy*vz - Qz*vy;
        float c1y = Qz*vx - Qx*vz;
        float c1z = Qx*vy - Qy*vx;
        float c2x = Qw*c1x + (Qy*c1z - Qz*c1y);
        float c2y = Qw*c1y + (Qz*c1x - Qx*c1z);
        float c2z = Qw*c1z + (Qx*c1y - Qy*c1x);
        tx += vx + 2.0f*c2x;
        ty += vy + 2.0f*c2y;
        tz += vz + 2.0f*c2z;
        // qstep = cv*qj + sv*qjw   (8 ops)
        float sw = cv[j]*c[0] + sv[j]*c[4];
        float sx = cv[j]*c[1] + sv[j]*c[5];
        float sy = cv[j]*c[2] + sv[j]*c[6];
        float sz = cv[j]*c[3] + sv[j]*c[7];
        // Q = Q ⊗ qstep
        float nw = Qw*sw - Qx*sx - Qy*sy - Qz*sz;
        float nx = Qw*sx + Qx*sw + Qy*sz - Qz*sy;
        float ny = Qw*sy - Qx*sz + Qy*sw + Qz*sx;
        float nz = Qw*sz + Qx*sy - Qy*sx + Qz*sw;
        Qw = nw; Qx = nx; Qy = ny; Qz = nz;
    }

    // Q -> rotation matrix
    float xx = Qx*Qx, yy = Qy*Qy, zz = Qz*Qz;
    float xy = Qx*Qy, xz = Qx*Qz, yz = Qy*Qz;
    float wx = Qw*Qx, wy = Qw*Qy, wz = Qw*Qz;
    float M00 = 1.0f - 2.0f*(yy+zz);
    float M01 = 2.0f*(xy - wz);
    float M02 = 2.0f*(xz + wy);
    float M10 = 2.0f*(xy + wz);
    float M11 = 1.0f - 2.0f*(xx+zz);
    float M12 = 2.0f*(yz - wx);
    float M20 = 2.0f*(xz - wy);
    float M21 = 2.0f*(yz + wx);
    float M22 = 1.0f - 2.0f*(xx+yy);

    const float px = cst[FK_NQ*JREC+0], py = cst[FK_NQ*JREC+1], pz = cst[FK_NQ*JREC+2];
    float4* o = (float4*)(out + (long)b * 16);
    o[0] = make_float4(M00, M01, M02, M00*px + M01*py + M02*pz + tx);
    o[1] = make_float4(M10, M11, M12, M10*px + M11*py + M12*pz + ty);
    o[2] = make_float4(M20, M21, M22, M20*px + M21*py + M22*pz + tz);
    o[3] = make_float4(0.0f, 0.0f, 0.0f, 1.0f);
}

extern "C" void kernel_launch(void* const* d_in, const int* in_sizes, int n_in,
                              void* d_out, int out_size, void* d_ws, size_t ws_size,
                              hipStream_t stream) {
    const float* q          = (const float*)d_in[0];
    const float* joint_xyz  = (const float*)d_in[1];
    const float* joint_rpy  = (const float*)d_in[2];
    const float* joint_axis = (const float*)d_in[3];
    const float* link_xyz   = (const float*)d_in[4];
    const int*   idxp       = (const int*)d_in[5];
    float* out = (float*)d_out;
    float* cst = (float*)d_ws;

    const int nb = in_sizes[0] / FK_NQ;
    const int grid = (nb + FK_BLOCK - 1) / FK_BLOCK;

    fk_setup<<<1, 64, 0, stream>>>(joint_xyz, joint_rpy, joint_axis,
                                   link_xyz, idxp, cst);
    fk_main<<<grid, FK_BLOCK, 0, stream>>>(q, cst, out, nb);
}

// Round 6
// 21.712 us; speedup vs baseline: 1.6361x; 1.1596x over previous
//
#include <hip/hip_runtime.h>

#define FK_NQ 7
#define FK_BLOCK 256

// Per-joint LDS record: 3 float4 at c4[j*3 + {0,1,2}]
//   [0] qj  = quat(R_joint)              (w,x,y,z)
//   [1] qjw = qj (x) (0, w/|w|)          (w,x,y,z)
//   [2] (t_j.x, t_j.y, t_j.z, 0.5*|w|)
// c4[21] = (px, py, pz, 0)  -- link_xyz[idx]
//
// Joint j rotation quaternion: cos(halfn*th)*qj + sin(halfn*th)*qjw
//   == quat(R_joint_j) (x) quat(Rodrigues(w, th))

__device__ __forceinline__ void qmul(const float* a, const float* b, float* r)
{
    r[0] = a[0]*b[0] - a[1]*b[1] - a[2]*b[2] - a[3]*b[3];
    r[1] = a[0]*b[1] + a[1]*b[0] + a[2]*b[3] - a[3]*b[2];
    r[2] = a[0]*b[2] - a[1]*b[3] + a[2]*b[0] + a[3]*b[1];
    r[3] = a[0]*b[3] + a[1]*b[2] - a[2]*b[1] + a[3]*b[0];
}

__global__ __launch_bounds__(FK_BLOCK, 8) void fk_fused(
    const float* __restrict__ q,
    const float* __restrict__ joint_xyz,
    const float* __restrict__ joint_rpy,
    const float* __restrict__ joint_axis,
    const float* __restrict__ link_xyz,
    const int*   __restrict__ idxp,
    float* __restrict__ out,
    unsigned nb)
{
    __shared__ float4 c4[22];

    const int tid = threadIdx.x;
    const unsigned b = blockIdx.x * FK_BLOCK + tid;
    const bool valid = (b < nb);

    // Issue the per-thread q loads FIRST: independent of LDS, their HBM
    // latency overlaps the setup lanes' work + barrier.
    float th[FK_NQ];
    if (valid) {
        const float* qp = q + b * FK_NQ;   // b*7 < 2^22, 32-bit math
        #pragma unroll
        for (int j = 0; j < FK_NQ; ++j) th[j] = qp[j];
    }

    // Lanes 0..6: build joint records; lane 7: link offset.
    if (tid < FK_NQ) {
        const int j = tid;
        float rr = joint_rpy[j*3+0], pp = joint_rpy[j*3+1], yy = joint_rpy[j*3+2];
        float sr, cr, sp2, cp2, sy, cy;
        __sincosf(0.5f*rr, &sr, &cr);
        __sincosf(0.5f*pp, &sp2, &cp2);
        __sincosf(0.5f*yy, &sy, &cy);
        float qx[4] = {cr, sr, 0.f, 0.f};
        float qy[4] = {cp2, 0.f, sp2, 0.f};
        float qz[4] = {cy, 0.f, 0.f, sy};
        float tmp[4], qj[4];
        qmul(qy, qx, tmp);
        qmul(qz, tmp, qj);

        float w0 = joint_axis[j*3+0], w1 = joint_axis[j*3+1], w2 = joint_axis[j*3+2];
        float n  = sqrtf(w0*w0 + w1*w1 + w2*w2);
        float ninv = 1.0f/n;
        float qu[4] = {0.f, w0*ninv, w1*ninv, w2*ninv};
        float qjw[4];
        qmul(qj, qu, qjw);

        c4[j*3+0] = make_float4(qj[0],  qj[1],  qj[2],  qj[3]);
        c4[j*3+1] = make_float4(qjw[0], qjw[1], qjw[2], qjw[3]);
        c4[j*3+2] = make_float4(joint_xyz[j*3+0], joint_xyz[j*3+1],
                                joint_xyz[j*3+2], 0.5f*n);
    } else if (tid == FK_NQ) {
        const int ix = idxp[0];
        c4[21] = make_float4(link_xyz[ix*3+0], link_xyz[ix*3+1],
                             link_xyz[ix*3+2], 0.0f);
    }
    __syncthreads();

    if (!valid) return;

    // j = 0
    float4 j0q = c4[0], j0w = c4[1], j0t = c4[2];
    float sv, cv;
    __sincosf(j0t.w * th[0], &sv, &cv);
    float Qw = cv*j0q.x + sv*j0w.x;
    float Qx = cv*j0q.y + sv*j0w.y;
    float Qy = cv*j0q.z + sv*j0w.z;
    float Qz = cv*j0q.w + sv*j0w.w;
    float tx = j0t.x, ty = j0t.y, tz = j0t.z;

    #pragma unroll
    for (int j = 1; j < FK_NQ; ++j) {
        float4 jq = c4[j*3+0], jw = c4[j*3+1], jt = c4[j*3+2];
        float s, c;
        __sincosf(jt.w * th[j], &s, &c);
        // t += R(Q) * t_j   (v + 2(w*(u×v) + u×(u×v)))
        float vx = jt.x, vy = jt.y, vz = jt.z;
        float c1x = Qy*vz - Qz*vy;
        float c1y = Qz*vx - Qx*vz;
        float c1z = Qx*vy - Qy*vx;
        float c2x = Qw*c1x + (Qy*c1z - Qz*c1y);
        float c2y = Qw*c1y + (Qz*c1x - Qx*c1z);
        float c2z = Qw*c1z + (Qx*c1y - Qy*c1x);
        tx += vx + 2.0f*c2x;
        ty += vy + 2.0f*c2y;
        tz += vz + 2.0f*c2z;
        // qstep = c*qj + s*qjw
        float sw = c*jq.x + s*jw.x;
        float sx = c*jq.y + s*jw.y;
        float sy = c*jq.z + s*jw.z;
        float sz = c*jq.w + s*jw.w;
        // Q = Q (x) qstep
        float nw = Qw*sw - Qx*sx - Qy*sy - Qz*sz;
        float nx = Qw*sx + Qx*sw + Qy*sz - Qz*sy;
        float ny = Qw*sy - Qx*sz + Qy*sw + Qz*sx;
        float nz = Qw*sz + Qx*sy - Qy*sx + Qz*sw;
        Qw = nw; Qx = nx; Qy = ny; Qz = nz;
    }

    // Q -> rotation matrix
    float xx = Qx*Qx, yy = Qy*Qy, zz = Qz*Qz;
    float xy = Qx*Qy, xz = Qx*Qz, yz = Qy*Qz;
    float wx = Qw*Qx, wy = Qw*Qy, wz = Qw*Qz;
    float M00 = 1.0f - 2.0f*(yy+zz);
    float M01 = 2.0f*(xy - wz);
    float M02 = 2.0f*(xz + wy);
    float M10 = 2.0f*(xy + wz);
    float M11 = 1.0f - 2.0f*(xx+zz);
    float M12 = 2.0f*(yz - wx);
    float M20 = 2.0f*(xz - wy);
    float M21 = 2.0f*(yz + wx);
    float M22 = 1.0f - 2.0f*(xx+yy);

    float4 lp = c4[21];
    float4* o = (float4*)(out + (size_t)b * 16u);
    o[0] = make_float4(M00, M01, M02, M00*lp.x + M01*lp.y + M02*lp.z + tx);
    o[1] = make_float4(M10, M11, M12, M10*lp.x + M11*lp.y + M12*lp.z + ty);
    o[2] = make_float4(M20, M21, M22, M20*lp.x + M21*lp.y + M22*lp.z + tz);
    o[3] = make_float4(0.0f, 0.0f, 0.0f, 1.0f);
}

extern "C" void kernel_launch(void* const* d_in, const int* in_sizes, int n_in,
                              void* d_out, int out_size, void* d_ws, size_t ws_size,
                              hipStream_t stream) {
    const float* q          = (const float*)d_in[0];
    const float* joint_xyz  = (const float*)d_in[1];
    const float* joint_rpy  = (const float*)d_in[2];
    const float* joint_axis = (const float*)d_in[3];
    const float* link_xyz   = (const float*)d_in[4];
    const int*   idxp       = (const int*)d_in[5];
    float* out = (float*)d_out;

    const unsigned nb = (unsigned)(in_sizes[0] / FK_NQ);
    const int grid = (int)((nb + FK_BLOCK - 1) / FK_BLOCK);

    fk_fused<<<grid, FK_BLOCK, 0, stream>>>(q, joint_xyz, joint_rpy, joint_axis,
                                            link_xyz, idxp, out, nb);
}